// Round 3
// baseline (247.337 us; speedup 1.0000x reference)
//
#include <hip/hip_runtime.h>
#include <hip/hip_bf16.h>
#include <stdint.h>

typedef __hip_bfloat16 bf16;
typedef __attribute__((ext_vector_type(8))) short short8;   // 8 bf16 = 4 VGPRs (MFMA A/B frag)
typedef __attribute__((ext_vector_type(4))) float floatx4;  // MFMA C/D frag

#define AS1(p) ((const __attribute__((address_space(1))) void*)(p))
#define AS3(p) ((__attribute__((address_space(3))) void*)(p))

#define M_DIM 4096
#define H_DIM 1024
#define MEG   (1u << 20)   // 1M elements

// fp32 -> bf16 bits, round-to-nearest-even (inputs are finite)
__device__ __forceinline__ unsigned short f2bf(float f) {
    uint32_t u = __float_as_uint(f);
    uint32_t r = (u + 0x7FFFu + ((u >> 16) & 1u)) >> 16;
    return (unsigned short)r;
}

__device__ __forceinline__ float fast_sigmoid(float v) {
    return 1.0f / (1.0f + __expf(-v));
}
__device__ __forceinline__ float fast_tanh(float v) {
    return 2.0f / (1.0f + __expf(-2.0f * v)) - 1.0f;
}

// ---------------------------------------------------------------------------
// Kernel 1: convert fp32 inputs -> bf16 in workspace.
// ws layout (bf16 elems): x [0,4M) | h [4M,8M) | Wx{f,i,o,c} [8M+g*1M) |
//                         Wh{f,i,o,c} [12M+g*1M).  16M elems = 32 MB.
__global__ __launch_bounds__(256)
void convert_to_bf16(const float* __restrict__ x, const float* __restrict__ h,
                     const float* Wxf, const float* Wxi, const float* Wxo, const float* Wxc,
                     const float* Whf, const float* Whi, const float* Who, const float* Whc,
                     unsigned short* __restrict__ ws)
{
    const uint32_t idx0 = blockIdx.x * 2048u + threadIdx.x * 8u;
    const uint32_t t = blockIdx.x >> 9;   // 512 blocks per 1M elements (block-uniform)
    const float* src;
    uint32_t off;
    if (t < 4u)      { src = x; off = idx0; }
    else if (t < 8u) { src = h; off = idx0 - (4u << 20); }
    else {
        const uint32_t g = t - 8u;
        src = (g == 0) ? Wxf : (g == 1) ? Wxi : (g == 2) ? Wxo : (g == 3) ? Wxc
            : (g == 4) ? Whf : (g == 5) ? Whi : (g == 6) ? Who : Whc;
        off = idx0 & (MEG - 1u);
    }
    const float4 v0 = *(const float4*)(src + off);
    const float4 v1 = *(const float4*)(src + off + 4);
    short8 pk;
    pk[0] = (short)f2bf(v0.x); pk[1] = (short)f2bf(v0.y);
    pk[2] = (short)f2bf(v0.z); pk[3] = (short)f2bf(v0.w);
    pk[4] = (short)f2bf(v1.x); pk[5] = (short)f2bf(v1.y);
    pk[6] = (short)f2bf(v1.z); pk[7] = (short)f2bf(v1.w);
    *(short8*)(ws + idx0) = pk;
}

// ---------------------------------------------------------------------------
// Kernel 2: fused 4-gate GEMM + LSTM pointwise.  m97-shaped config:
// Block: 256 threads (4 waves). Tile: 128 batch-rows x 32 hidden-cols x 4 gates
// (= effective 128x128 output tile).  Grid 32x32 = 1024 blocks = 4/CU.
// K loop: 64 steps of BK=32; phase 0 = x @ Wx^T, phase 1 = h @ Wh^T (accumulated).
// Wave w: rows (w&1)*64..+64 (4 m-tiles), cols (w>>1)*16..+16 (1 n-tile), all 4 gates.
// Per wave per K-step: 4 A-frags + 4 B-frags (ds_read_b128), 16 MFMAs — m97's shape.
__global__ __launch_bounds__(256, 2)
void lstm_fused_kernel(const unsigned short* __restrict__ ws,
                       const float* __restrict__ c,
                       const float* __restrict__ bxf, const float* __restrict__ bhf,
                       const float* __restrict__ bxi, const float* __restrict__ bhi,
                       const float* __restrict__ bxo, const float* __restrict__ bho,
                       const float* __restrict__ bxc, const float* __restrict__ bhc,
                       float* __restrict__ out)
{
    // LDS: A [128][32] bf16 (8 KB) + B [4 gates][32][32] bf16 (8 KB). Unpadded
    // row-major (global_load_lds dest = wave-uniform base + lane*16 — no padding).
    __shared__ __align__(16) char lds[16384];
    const bf16* ldsA = (const bf16*)lds;
    const bf16* ldsB = (const bf16*)(lds + 8192);

    const int tid  = threadIdx.x;
    const int w    = tid >> 6;
    const int lane = tid & 63;

    const int bm0 = blockIdx.x * 128;
    const int bn0 = blockIdx.y * 32;

    // staging: 16 chunks of 1 KB (16 rows x 32 k x 2B); wave w issues ch = w*4+i.
    // ch<8: A rows [ch*16,+16); ch>=8: b=ch-8, gate g=b>>1, n-subtile (b&1)*16.
    const unsigned short* srcP0[4];
    const unsigned short* srcP1[4];
    uint32_t goff[4];   // per-lane element offset within source
    uint32_t loff[4];   // wave-uniform LDS byte base
#pragma unroll
    for (int i = 0; i < 4; ++i) {
        const int ch = w * 4 + i;
        if (ch < 8) {
            const int row = bm0 + ch * 16 + (lane >> 2);
            srcP0[i] = ws;                 // x
            srcP1[i] = ws + (4u << 20);    // h
            goff[i] = (uint32_t)row * 1024u + (uint32_t)(lane & 3) * 8u;
            loff[i] = (uint32_t)ch * 1024u;
        } else {
            const int b = ch - 8;
            const int g = b >> 1;
            const int n = bn0 + (b & 1) * 16 + (lane >> 2);
            srcP0[i] = ws + (8u << 20)  + (uint32_t)g * MEG;   // Wx_g
            srcP1[i] = ws + (12u << 20) + (uint32_t)g * MEG;   // Wh_g
            goff[i] = (uint32_t)n * 1024u + (uint32_t)(lane & 3) * 8u;
            loff[i] = 8192u + (uint32_t)b * 1024u;
        }
    }

    const int wrow  = (w & 1) * 64;    // 4 m-tiles
    const int wcol  = (w >> 1) * 16;   // 1 n-tile
    const int lrc   = lane & 15;       // frag row (A) / col (B)
    const int lquad = lane >> 4;       // frag k-offset = lquad*8

    uint32_t aoff[4];
#pragma unroll
    for (int mt = 0; mt < 4; ++mt)
        aoff[mt] = (uint32_t)((wrow + mt * 16 + lrc) * 32 + lquad * 8);
    uint32_t boff[4];
#pragma unroll
    for (int g = 0; g < 4; ++g)
        boff[g] = (uint32_t)(g * 1024 + (wcol + lrc) * 32 + lquad * 8);

    floatx4 acc[4][4];   // [gate][m-tile] = 64 fp32/lane
#pragma unroll
    for (int g = 0; g < 4; ++g)
#pragma unroll
        for (int mt = 0; mt < 4; ++mt)
            acc[g][mt] = (floatx4){0.f, 0.f, 0.f, 0.f};

    for (int kt = 0; kt < 64; ++kt) {
        const int phase = kt >> 5;
        const uint32_t k0 = (uint32_t)(kt & 31) * 32u;
#pragma unroll
        for (int i = 0; i < 4; ++i) {
            const unsigned short* src = phase ? srcP1[i] : srcP0[i];
            __builtin_amdgcn_global_load_lds(AS1(src + goff[i] + k0),
                                             AS3(lds + loff[i]), 16, 0, 0);
        }
        asm volatile("s_waitcnt vmcnt(0)" ::: "memory");  // drain LDS-DMA before barrier
        __syncthreads();

        short8 afr[4];
#pragma unroll
        for (int mt = 0; mt < 4; ++mt)
            afr[mt] = *(const short8*)(ldsA + aoff[mt]);
#pragma unroll
        for (int g = 0; g < 4; ++g) {
            const short8 bfr = *(const short8*)(ldsB + boff[g]);
#pragma unroll
            for (int mt = 0; mt < 4; ++mt)
                acc[g][mt] = __builtin_amdgcn_mfma_f32_16x16x32_bf16(
                    afr[mt], bfr, acc[g][mt], 0, 0, 0);
        }
        __syncthreads();
    }

    // epilogue.  C/D layout: col = lane&15, row = (lane>>4)*4 + reg
    float* out_ct = out;
    float* out_ht = out + (size_t)M_DIM * H_DIM;
    {
        const int col = bn0 + wcol + lrc;
        const float bf_ = bxf[col] + bhf[col];
        const float bi_ = bxi[col] + bhi[col];
        const float bo_ = bxo[col] + bho[col];
        const float bc_ = bxc[col] + bhc[col];
#pragma unroll
        for (int mt = 0; mt < 4; ++mt) {
#pragma unroll
            for (int r = 0; r < 4; ++r) {
                const int row = bm0 + wrow + mt * 16 + lquad * 4 + r;
                const float gf = acc[0][mt][r] + bf_;
                const float gi = acc[1][mt][r] + bi_;
                const float go = acc[2][mt][r] + bo_;
                const float gc = acc[3][mt][r] + bc_;
                const float f    = fast_sigmoid(gf);
                const float ii   = fast_sigmoid(gi);
                const float o    = fast_sigmoid(go);
                const float ctil = fast_tanh(gc);
                const float cv   = c[(size_t)row * H_DIM + col];
                const float ctn  = f * cv + ctil * ii;
                const float htn  = fast_tanh(ctn) * o;
                out_ct[(size_t)row * H_DIM + col] = ctn;
                out_ht[(size_t)row * H_DIM + col] = htn;
            }
        }
    }
}

extern "C" void kernel_launch(void* const* d_in, const int* in_sizes, int n_in,
                              void* d_out, int out_size, void* d_ws, size_t ws_size,
                              hipStream_t stream) {
    (void)in_sizes; (void)n_in; (void)out_size; (void)ws_size;
    const float* x   = (const float*)d_in[0];
    const float* c   = (const float*)d_in[1];
    const float* h   = (const float*)d_in[2];
    const float* Wxf = (const float*)d_in[3];  const float* bxf = (const float*)d_in[4];
    const float* Whf = (const float*)d_in[5];  const float* bhf = (const float*)d_in[6];
    const float* Wxi = (const float*)d_in[7];  const float* bxi = (const float*)d_in[8];
    const float* Whi = (const float*)d_in[9];  const float* bhi = (const float*)d_in[10];
    const float* Wxo = (const float*)d_in[11]; const float* bxo = (const float*)d_in[12];
    const float* Who = (const float*)d_in[13]; const float* bho = (const float*)d_in[14];
    const float* Wxc = (const float*)d_in[15]; const float* bxc = (const float*)d_in[16];
    const float* Whc = (const float*)d_in[17]; const float* bhc = (const float*)d_in[18];
    float* out = (float*)d_out;
    unsigned short* ws = (unsigned short*)d_ws;   // 16M bf16 elements = 32 MB

    convert_to_bf16<<<8192, 256, 0, stream>>>(x, h,
        Wxf, Wxi, Wxo, Wxc, Whf, Whi, Who, Whc, ws);

    dim3 grid(M_DIM / 128, H_DIM / 32);   // 32 x 32 = 1024 blocks (4/CU grid-side)
    lstm_fused_kernel<<<grid, 256, 0, stream>>>(ws, c,
        bxf, bhf, bxi, bhi, bxo, bho, bxc, bhc, out);
}

// Round 4
// 222.888 us; speedup vs baseline: 1.1097x; 1.1097x over previous
//
#include <hip/hip_runtime.h>
#include <hip/hip_bf16.h>
#include <stdint.h>

typedef __hip_bfloat16 bf16;
typedef __attribute__((ext_vector_type(8))) short short8;   // 8 bf16 = 4 VGPRs (MFMA A/B frag)
typedef __attribute__((ext_vector_type(4))) float floatx4;  // MFMA C/D frag

#define AS1(p) ((const __attribute__((address_space(1))) void*)(p))
#define AS3(p) ((__attribute__((address_space(3))) void*)(p))

#define M_DIM 4096
#define H_DIM 1024
#define MEG   (1u << 20)    // 1M elements
#define LDS_BUF 24576       // one pipeline stage: A 8KB + B 16KB

// fp32 -> bf16 bits, round-to-nearest-even (inputs are finite)
__device__ __forceinline__ unsigned short f2bf(float f) {
    uint32_t u = __float_as_uint(f);
    uint32_t r = (u + 0x7FFFu + ((u >> 16) & 1u)) >> 16;
    return (unsigned short)r;
}

__device__ __forceinline__ float fast_sigmoid(float v) {
    return 1.0f / (1.0f + __expf(-v));
}
__device__ __forceinline__ float fast_tanh(float v) {
    return 2.0f / (1.0f + __expf(-2.0f * v)) - 1.0f;
}

// ---------------------------------------------------------------------------
// Kernel 1: convert fp32 inputs -> bf16 in workspace.
// ws layout (bf16 elems): x [0,4M) | h [4M,8M) | Wx{f,i,o,c} [8M+g*1M) |
//                         Wh{f,i,o,c} [12M+g*1M).  16M elems = 32 MB.
__global__ __launch_bounds__(256)
void convert_to_bf16(const float* __restrict__ x, const float* __restrict__ h,
                     const float* Wxf, const float* Wxi, const float* Wxo, const float* Wxc,
                     const float* Whf, const float* Whi, const float* Who, const float* Whc,
                     unsigned short* __restrict__ ws)
{
    const uint32_t idx0 = blockIdx.x * 2048u + threadIdx.x * 8u;
    const uint32_t t = blockIdx.x >> 9;   // 512 blocks per 1M elements (block-uniform)
    const float* src;
    uint32_t off;
    if (t < 4u)      { src = x; off = idx0; }
    else if (t < 8u) { src = h; off = idx0 - (4u << 20); }
    else {
        const uint32_t g = t - 8u;
        src = (g == 0) ? Wxf : (g == 1) ? Wxi : (g == 2) ? Wxo : (g == 3) ? Wxc
            : (g == 4) ? Whf : (g == 5) ? Whi : (g == 6) ? Who : Whc;
        off = idx0 & (MEG - 1u);
    }
    const float4 v0 = *(const float4*)(src + off);
    const float4 v1 = *(const float4*)(src + off + 4);
    short8 pk;
    pk[0] = (short)f2bf(v0.x); pk[1] = (short)f2bf(v0.y);
    pk[2] = (short)f2bf(v0.z); pk[3] = (short)f2bf(v0.w);
    pk[4] = (short)f2bf(v1.x); pk[5] = (short)f2bf(v1.y);
    pk[6] = (short)f2bf(v1.z); pk[7] = (short)f2bf(v1.w);
    *(short8*)(ws + idx0) = pk;
}

// ---------------------------------------------------------------------------
// Kernel 2: fused 4-gate GEMM + LSTM pointwise, software-pipelined.
// Block: 256 threads (4 waves). Tile: 128 batch-rows x 64 hidden-cols x 4 gates.
// K loop: 64 steps of BK=32; phase 0 = x @ Wx^T, phase 1 = h @ Wh^T (accumulated).
// Double-buffered LDS (2 x 24KB) + raw s_barrier + s_waitcnt vmcnt(6): iter k+1's
// 6 staging loads stay in flight across the barrier, landing during iter k's
// 32 MFMAs — the fine-vmcnt pipeline m97's __syncthreads structure can't express.
// LDS k-group XOR swizzle (slot = kgrp ^ ((row>>1)&3)) applied on the DMA source
// side kills the 4-extra-cycle ds_read_b128 bank conflicts (max 2-way = free).
__global__ __launch_bounds__(256, 2)
void lstm_fused_kernel(const unsigned short* __restrict__ ws,
                       const float* __restrict__ c,
                       const float* __restrict__ bxf, const float* __restrict__ bhf,
                       const float* __restrict__ bxi, const float* __restrict__ bhi,
                       const float* __restrict__ bxo, const float* __restrict__ bho,
                       const float* __restrict__ bxc, const float* __restrict__ bhc,
                       float* __restrict__ out)
{
    // Per stage: A [128][32] bf16 (8 KB) + B [4 gates][64][32] bf16 (16 KB).
    __shared__ __align__(16) char lds[2 * LDS_BUF];

    const int tid  = threadIdx.x;
    const int w    = tid >> 6;
    const int lane = tid & 63;

    const int bm0 = blockIdx.x * 128;
    const int bn0 = blockIdx.y * 64;

    // staging: 24 chunks of 1 KB (16 rows x 32 k x 2B); wave w issues ch = w*6+i.
    // ch<8: A rows [ch*16,+16); ch>=8: b=ch-8, gate g=b>>2, n-subtile (b&3)*16.
    // Swizzled k-group: LDS slot (lane&3) holds global k-group (lane&3)^((lane>>3)&3)
    // (row_local = lane>>2, t(row) = (row>>1)&3 = (lane>>3)&3).
    const uint32_t cg = (((uint32_t)lane & 3u) ^ (((uint32_t)lane >> 3) & 3u)) * 8u;
    const unsigned short* srcP0[6];
    const unsigned short* srcP1[6];
    uint32_t goff[6];   // per-lane element offset within source
    uint32_t loff[6];   // wave-uniform LDS byte base (within a stage)
#pragma unroll
    for (int i = 0; i < 6; ++i) {
        const int ch = w * 6 + i;
        if (ch < 8) {
            const int row = bm0 + ch * 16 + (lane >> 2);
            srcP0[i] = ws;                 // x
            srcP1[i] = ws + (4u << 20);    // h
            goff[i] = (uint32_t)row * 1024u + cg;
            loff[i] = (uint32_t)ch * 1024u;
        } else {
            const int b = ch - 8;
            const int g = b >> 2;
            const int n = bn0 + (b & 3) * 16 + (lane >> 2);
            srcP0[i] = ws + (8u << 20)  + (uint32_t)g * MEG;   // Wx_g
            srcP1[i] = ws + (12u << 20) + (uint32_t)g * MEG;   // Wh_g
            goff[i] = (uint32_t)n * 1024u + cg;
            loff[i] = 8192u + (uint32_t)b * 1024u;
        }
    }

    const int wrow  = (w & 1) * 64;    // 4 m-tiles
    const int wcol  = (w >> 1) * 32;   // 2 n-tiles
    const int lrc   = lane & 15;       // frag row (A) / col (B)
    const int lquad = lane >> 4;       // frag k-group (x8 elements)

    // reader-side swizzle: global k-group lquad of row r lives at slot lquad^((r>>1)&3);
    // (r>>1)&3 == (lrc>>1)&3 for all mt/nt (tile offsets only touch bits >=4).
    const uint32_t kslot = (((uint32_t)lquad ^ (((uint32_t)lrc >> 1) & 3u))) * 8u;

    uint32_t aoff[4];
#pragma unroll
    for (int mt = 0; mt < 4; ++mt)
        aoff[mt] = (uint32_t)((wrow + mt * 16 + lrc) * 32) + kslot;
    uint32_t boff[4][2];
#pragma unroll
    for (int g = 0; g < 4; ++g)
#pragma unroll
        for (int nt = 0; nt < 2; ++nt)
            boff[g][nt] = (uint32_t)(g * 2048 + (wcol + nt * 16 + lrc) * 32) + kslot;

    floatx4 acc[4][4][2];
#pragma unroll
    for (int g = 0; g < 4; ++g)
#pragma unroll
        for (int mt = 0; mt < 4; ++mt)
#pragma unroll
            for (int nt = 0; nt < 2; ++nt)
                acc[g][mt][nt] = (floatx4){0.f, 0.f, 0.f, 0.f};

    auto issue_loads = [&](int kt) {
        const int phase = kt >> 5;
        const uint32_t k0 = (uint32_t)(kt & 31) * 32u;
        const uint32_t bb = (uint32_t)(kt & 1) * LDS_BUF;
#pragma unroll
        for (int i = 0; i < 6; ++i) {
            const unsigned short* src = phase ? srcP1[i] : srcP0[i];
            __builtin_amdgcn_global_load_lds(AS1(src + goff[i] + k0),
                                             AS3(lds + bb + loff[i]), 16, 0, 0);
        }
    };
    auto compute = [&](int kt) {
        const char* base = lds + (uint32_t)(kt & 1) * LDS_BUF;
        const bf16* lA = (const bf16*)base;
        const bf16* lB = (const bf16*)(base + 8192);
        short8 afr[4];
#pragma unroll
        for (int mt = 0; mt < 4; ++mt)
            afr[mt] = *(const short8*)(lA + aoff[mt]);
#pragma unroll
        for (int g = 0; g < 4; ++g) {
#pragma unroll
            for (int nt = 0; nt < 2; ++nt) {
                const short8 bfr = *(const short8*)(lB + boff[g][nt]);
#pragma unroll
                for (int mt = 0; mt < 4; ++mt)
                    acc[g][mt][nt] = __builtin_amdgcn_mfma_f32_16x16x32_bf16(
                        afr[mt], bfr, acc[g][mt][nt], 0, 0, 0);
            }
        }
    };

    // prologue: loads(0) -> buf0, full drain once
    issue_loads(0);
    asm volatile("s_waitcnt vmcnt(0)\ns_barrier" ::: "memory");

    for (int kt = 0; kt < 63; ++kt) {
        issue_loads(kt + 1);   // prefetch into the other buffer (WAR-safe: barrier below ended last read)
        // wait own 6 older loads (iter kt) retired; kt+1's 6 stay in flight across the barrier
        asm volatile("s_waitcnt vmcnt(6)\ns_barrier" ::: "memory");
        compute(kt);
        // all waves done reading buf[kt&1] before iter kt+1 overwrites it
        asm volatile("s_waitcnt lgkmcnt(0)\ns_barrier" ::: "memory");
    }
    asm volatile("s_waitcnt vmcnt(0)\ns_barrier" ::: "memory");
    compute(63);

    // epilogue.  C/D layout: col = lane&15, row = (lane>>4)*4 + reg
    float* out_ct = out;
    float* out_ht = out + (size_t)M_DIM * H_DIM;
#pragma unroll
    for (int nt = 0; nt < 2; ++nt) {
        const int col = bn0 + wcol + nt * 16 + lrc;
        const float bf_ = bxf[col] + bhf[col];
        const float bi_ = bxi[col] + bhi[col];
        const float bo_ = bxo[col] + bho[col];
        const float bc_ = bxc[col] + bhc[col];
#pragma unroll
        for (int mt = 0; mt < 4; ++mt) {
#pragma unroll
            for (int r = 0; r < 4; ++r) {
                const int row = bm0 + wrow + mt * 16 + lquad * 4 + r;
                const float gf = acc[0][mt][nt][r] + bf_;
                const float gi = acc[1][mt][nt][r] + bi_;
                const float go = acc[2][mt][nt][r] + bo_;
                const float gc = acc[3][mt][nt][r] + bc_;
                const float f    = fast_sigmoid(gf);
                const float ii   = fast_sigmoid(gi);
                const float o    = fast_sigmoid(go);
                const float ctil = fast_tanh(gc);
                const float cv   = c[(size_t)row * H_DIM + col];
                const float ctn  = f * cv + ctil * ii;
                const float htn  = fast_tanh(ctn) * o;
                out_ct[(size_t)row * H_DIM + col] = ctn;
                out_ht[(size_t)row * H_DIM + col] = htn;
            }
        }
    }
}

extern "C" void kernel_launch(void* const* d_in, const int* in_sizes, int n_in,
                              void* d_out, int out_size, void* d_ws, size_t ws_size,
                              hipStream_t stream) {
    (void)in_sizes; (void)n_in; (void)out_size; (void)ws_size;
    const float* x   = (const float*)d_in[0];
    const float* c   = (const float*)d_in[1];
    const float* h   = (const float*)d_in[2];
    const float* Wxf = (const float*)d_in[3];  const float* bxf = (const float*)d_in[4];
    const float* Whf = (const float*)d_in[5];  const float* bhf = (const float*)d_in[6];
    const float* Wxi = (const float*)d_in[7];  const float* bxi = (const float*)d_in[8];
    const float* Whi = (const float*)d_in[9];  const float* bhi = (const float*)d_in[10];
    const float* Wxo = (const float*)d_in[11]; const float* bxo = (const float*)d_in[12];
    const float* Who = (const float*)d_in[13]; const float* bho = (const float*)d_in[14];
    const float* Wxc = (const float*)d_in[15]; const float* bxc = (const float*)d_in[16];
    const float* Whc = (const float*)d_in[17]; const float* bhc = (const float*)d_in[18];
    float* out = (float*)d_out;
    unsigned short* ws = (unsigned short*)d_ws;   // 16M bf16 elements = 32 MB

    convert_to_bf16<<<8192, 256, 0, stream>>>(x, h,
        Wxf, Wxi, Wxo, Wxc, Whf, Whi, Who, Whc, ws);

    dim3 grid(M_DIM / 128, H_DIM / 64);   // 32 x 16 = 512 blocks
    lstm_fused_kernel<<<grid, 256, 0, stream>>>(ws, c,
        bxf, bhf, bxi, bhi, bxo, bho, bxc, bhc, out);
}